// Round 15
// baseline (577.929 us; speedup 1.0000x reference)
//
#include <hip/hip_runtime.h>
#include <hip/hip_bf16.h>

#define DEVI __device__ __forceinline__

typedef short bf16x8 __attribute__((ext_vector_type(8)));
typedef float f32x4  __attribute__((ext_vector_type(4)));

static constexpr int Bb   = 128;
static constexpr int Ss   = 512;
static constexpr int Hh   = 1024;
static constexpr int Ee   = 512;
static constexpr int Vv   = 50257;
static constexpr int TWOH = 2048;

DEVI short f2bf(float f){ __hip_bfloat16 h = __float2bfloat16(f); return *reinterpret_cast<short*>(&h); }
DEVI float bf2f(short s){ __hip_bfloat16 h = *reinterpret_cast<__hip_bfloat16*>(&s); return __bfloat162float(h); }

DEVI float tanh_fast(float x){            // 1 - 2/(e^2x + 1): ±inf-safe, ~1e-7 rel err
  float e = __expf(2.0f*x);
  return 1.0f - 2.0f/(e + 1.0f);
}

DEVI bf16x8 pack8(f32x4 a, f32x4 b){
  bf16x8 v;
  v[0]=f2bf(a[0]); v[1]=f2bf(a[1]); v[2]=f2bf(a[2]); v[3]=f2bf(a[3]);
  v[4]=f2bf(b[0]); v[5]=f2bf(b[1]); v[6]=f2bf(b[2]); v[7]=f2bf(b[3]);
  return v;
}

DEVI void gld_lds16(const void* g, void* l){
  __builtin_amdgcn_global_load_lds((const __attribute__((address_space(1))) void*)g,
                                   (__attribute__((address_space(3))) void*)l, 16, 0, 0);
}

DEVI f32x4 mfma16(bf16x8 a, bf16x8 b, f32x4 c){
  return __builtin_amdgcn_mfma_f32_16x16x32_bf16(a, b, c, 0, 0, 0);
}

// ---------------- prep: convert W_ae->bf16, h->bf16, gather emb into x_bf16 ----------------
__global__ void k_prep(const float* __restrict__ wae, short* __restrict__ waeb,
                       const float* __restrict__ h, short* __restrict__ hb,
                       const int* __restrict__ dec_in, const float* __restrict__ emb,
                       short* __restrict__ xb)
{
  const int total_wae = Hh*TWOH;
  const int total_h   = Bb*Hh;
  const int total_emb = Bb*Ee;
  const int total = total_wae + total_h + total_emb;
  for (int i = blockIdx.x*blockDim.x + threadIdx.x; i < total; i += gridDim.x*blockDim.x){
    if (i < total_wae) waeb[i] = f2bf(wae[i]);
    else if (i < total_wae + total_h){ int j = i - total_wae; hb[j] = f2bf(h[j]); }
    else {
      int j = i - total_wae - total_h;
      int b = j >> 9, e = j & 511;
      xb[b*2560 + e] = f2bf(emb[(size_t)dec_in[b]*Ee + e]);
    }
  }
}

// ---------------- scores GEMM, FUSED conversion, 2-BLOCKS/CU geometry ------
// vs r14 (403us, MfmaUtil 29%, 1 block/CU): tile-step time 7560cyc vs 2300cyc
// LDS content -> latency/serialization-bound at 2 waves/SIMD with no second
// block to fill stalls (m114: implicit inter-block overlap is the lever).
// New geometry: 128x256 tile, BK=64, 8 waves (2Mx4N), per-wave 64x64
// (acc[4][4]=64 regs, pa[2][2]); launch_bounds(512,4) pins regs <=128.
// LDS 80KB = A single 16KB + B dbuf 2x32KB -> 2 blocks/CU, 4 waves/SIMD.
// Per tile: STB(t+1) pinned at top (full-tile cover, dbuf B); MFMA phase;
// barrier (A reads done); COMMITA (pa-wait retires PREFA(t+1), older, so
// STB stays in flight) + STOREE + PREFA(t+2); vmcnt(8) retires STB+STOREE,
// keeps PREFA's 8; lgkmcnt(0); barrier. A fp32 conversion fused (PREFA->
// pack8->ds_write); nb==0 blocks persist bf16 panel to encb for k_ctx.
// XCD map: q&7=xcd, rt=xcd*64+(sl>>2), nb=sl&3 (bijective); 4 nb-sharers of
// each 1MB fp32 A panel run concurrently on one XCD (hot set 16x32KB << L2).
__launch_bounds__(512, 4)
__global__ void k_scores_fuse(const float* __restrict__ enc, short* __restrict__ encb,
                              const short* __restrict__ waeb,
                              const float* __restrict__ ahb, const float* __restrict__ b_ah,
                              const float* __restrict__ b_ae, const float* __restrict__ wsc,
                              float* __restrict__ scores)
{
  __shared__ __align__(16) char LDSB[81920];    // A: 16KB @0, B: 2x32KB @16384
  const int q  = blockIdx.x;
  const int xcd = q & 7, sl = q >> 3;           // sl 0..255
  const int rt = xcd*64 + (sl>>2), nb = sl & 3; // rt 0..511, nb 0..3 (bijective)
  const int tid = threadIdx.x, wid = tid>>6, lane = tid&63;
  const int wr = wid>>2, wc = wid&3;            // 2M x 4N waves, per-wave 64x64
  const int srow = lane>>3, l7 = lane&7;
  const int lo = lane&15, hi4 = lane>>4;
  const int swk = (l7 ^ srow)*8;                // pre-swizzled source k-chunk (elems)

  const float* Ag = enc  + (size_t)rt*128*TWOH + (size_t)(wid*8+srow)*TWOH + swk;
  const short* Bg = waeb + (size_t)nb*256*TWOH + (size_t)(wid*8+srow)*TWOH + swk;
  short*       Eg = encb + (size_t)rt*128*TWOH + (size_t)(wid*8+srow)*TWOH + swk;
  const bool we = (nb == 0) && (encb != nullptr);

  char* AWc = LDSB + wid*1024 + lane*16;        // + rnd*8192 (ds_write, single buf)
  char* BW  = LDSB + 16384 + wid*1024;          // + bufB*32768 + rnd*8192 (gld_lds)
  const char* AR = LDSB + (wr*64 + lo)*128;     // + i*2048 + sw
  const char* BR = LDSB + 16384 + (wc*64 + lo)*128;  // + bufB*32768 + j*2048 + sw
  const int sw0 = (hi4*16) ^ (l7<<4);           // kk=0 swizzled byte offset
  const int sw1 = (64 + hi4*16) ^ (l7<<4);      // kk=1

  f32x4 acc[4][4] = {};
  f32x4 pa[2][2];                               // pending fp32 A regs (128 rows/tile)

  auto STB = [&](int buf, int kt){
    #pragma unroll
    for (int rnd=0; rnd<4; ++rnd)
      gld_lds16(Bg + (size_t)rnd*64*TWOH + kt*64, BW + buf*32768 + rnd*8192);
  };
  auto PREFA = [&](int kt){
    #pragma unroll
    for (int rnd=0; rnd<2; ++rnd){
      const float* p = Ag + (size_t)rnd*64*TWOH + kt*64;
      pa[rnd][0] = *(const f32x4*)p; pa[rnd][1] = *(const f32x4*)(p+4);
    }
  };
  auto COMMITA = [&](){
    #pragma unroll
    for (int rnd=0; rnd<2; ++rnd)
      *(bf16x8*)(AWc + rnd*8192) = pack8(pa[rnd][0], pa[rnd][1]);
  };
  auto STOREE = [&](int kt){
    #pragma unroll
    for (int rnd=0; rnd<2; ++rnd)
      *(bf16x8*)(Eg + (size_t)rnd*64*TWOH + kt*64) = pack8(pa[rnd][0], pa[rnd][1]);
  };

  // prologue: B(0)->buf0; A(0) regs -> commit (drains all, incl STB(0)); persist;
  // prefetch A(1); ds_writes drained; barrier.
  STB(0,0);
  PREFA(0); COMMITA();
  if (we) STOREE(0);
  PREFA(1);
  asm volatile("s_waitcnt lgkmcnt(0)" ::: "memory");
  __builtin_amdgcn_s_barrier();
  __builtin_amdgcn_sched_barrier(0);

  for (int t = 0; t < 32; ++t){
    const int bO = (t&1)*32768;
    bf16x8 af[4], bq[4];

    // ---- issue-early (pinned): B(t+1) into the other B buffer ----
    if (t<31) STB((t+1)&1, t+1);
    __builtin_amdgcn_sched_barrier(0);

    // ---- MFMA phase: kk0 then kk1, 32 MFMA total ----
    #pragma unroll
    for (int j=0;j<4;++j) bq[j] = *(const bf16x8*)(BR + bO + j*2048 + sw0);
    #pragma unroll
    for (int i=0;i<4;++i) af[i] = *(const bf16x8*)(AR + i*2048 + sw0);
    __builtin_amdgcn_s_setprio(1);
    #pragma unroll
    for (int i=0;i<4;++i)
      #pragma unroll
      for (int j=0;j<4;++j)
        acc[i][j] = mfma16(af[i], bq[j], acc[i][j]);
    __builtin_amdgcn_s_setprio(0);
    #pragma unroll
    for (int j=0;j<4;++j) bq[j] = *(const bf16x8*)(BR + bO + j*2048 + sw1);
    #pragma unroll
    for (int i=0;i<4;++i) af[i] = *(const bf16x8*)(AR + i*2048 + sw1);
    __builtin_amdgcn_s_setprio(1);
    #pragma unroll
    for (int i=0;i<4;++i)
      #pragma unroll
      for (int j=0;j<4;++j)
        acc[i][j] = mfma16(af[i], bq[j], acc[i][j]);
    __builtin_amdgcn_s_setprio(0);

    // ---- barrier: all waves done reading A (single buffer) ----
    __builtin_amdgcn_s_barrier();
    __builtin_amdgcn_sched_barrier(0);

    // ---- commit phase: A(t+1) regs -> LDS (+encb), prefetch A(t+2) ----
    if (t<31){
      COMMITA();                 // pa-wait retires PREFA(t+1) (older); STB survives
      if (we) STOREE(t+1);
      if (t<30) PREFA(t+2);
    }
    if (t<30)       asm volatile("s_waitcnt vmcnt(8)" ::: "memory"); // retire STB(+STOREE), keep PREFA
    else if (t==30) asm volatile("s_waitcnt vmcnt(0)" ::: "memory");
    asm volatile("s_waitcnt lgkmcnt(0)" ::: "memory");
    __builtin_amdgcn_s_barrier();
    __builtin_amdgcn_sched_barrier(0);
  }
  // epilogue: scores[m] += sum_n tanh(ah[b,n]+b_ah+b_ae+ae)*w_score[n]
  const int b = rt >> 2;                        // 128-row tile = quarter batch row
  float w4[4], t4[4];
  #pragma unroll
  for (int j=0;j<4;++j){
    int n = nb*256 + wc*64 + j*16 + lo;
    w4[j] = wsc[n];
    t4[j] = ahb[b*Hh + n] + b_ah[n] + b_ae[n];
  }
  #pragma unroll
  for (int i=0;i<4;++i){
    #pragma unroll
    for (int q2=0;q2<4;++q2){
      int m = rt*128 + wr*64 + i*16 + hi4*4 + q2;
      float s = 0.f;
      #pragma unroll
      for (int j=0;j<4;++j) s += tanh_fast(t4[j] + acc[i][j][q2]) * w4[j];
      s += __shfl_xor(s,1); s += __shfl_xor(s,2); s += __shfl_xor(s,4); s += __shfl_xor(s,8);
      if (lo == 0) atomicAdd(&scores[m], s);
    }
  }
}

// ---------------- generic 128-row GEMM: A[128,K] bf16 ws, B[N,K] fp32 global --------------
template<int MODE>
__launch_bounds__(256)
__global__ void k_gemm128(const short* __restrict__ A, int lda,
                          const float* __restrict__ B0, const float* __restrict__ B1,
                          float* __restrict__ O0, float* __restrict__ O1,
                          const float* __restrict__ bias, int kiters)
{
  __shared__ __align__(16) short As[2][128*64];
  __shared__ __align__(16) short Bs[2][128*64];
  const int nb = blockIdx.x;
  const int tid = threadIdx.x, wid = tid>>6, lane = tid&63;
  const int wr = wid>>1, wc = wid&1;
  const int srow = lane>>3, l7 = lane&7;
  const int swk = (l7 ^ srow) * 8;

  const float* Bt; int noff; float* Ot; int ostride;
  if constexpr (MODE==0){
    if (nb < 8){ Bt = B0; noff = 0;    Ot = O0; ostride = Hh;   }
    else       { Bt = B1; noff = 1024; Ot = O1; ostride = 3*Hh; }
  } else if constexpr (MODE==1){ Bt = B0; noff = 0; Ot = O0; ostride = 3*Hh; }
  else { Bt = B0; noff = 0; Ot = O0; ostride = Vv; }

  f32x4 acc[4][4] = {};
  f32x4 pb0[4], pb1[4];

  auto stageA = [&](int s, int kt){
    #pragma unroll
    for (int i=0;i<4;++i){
      int c = wid*4+i, row = c*8+srow;
      gld_lds16(A + (size_t)row*lda + kt*64 + swk, (char*)As[s] + c*1024);
    }
  };
  auto prefB = [&](int kt){
    #pragma unroll
    for (int i=0;i<4;++i){
      int row = (wid*4+i)*8+srow;
      int n = nb*128 + row - noff;
      if constexpr (MODE==2) n = (n > Vv-1) ? (Vv-1) : n;
      const float* bp = Bt + (size_t)n*lda + kt*64 + l7*8;
      pb0[i] = *(const f32x4*)bp; pb1[i] = *(const f32x4*)(bp+4);
    }
  };
  auto commitB = [&](int s){
    #pragma unroll
    for (int i=0;i<4;++i){
      int row = (wid*4+i)*8+srow;
      *(bf16x8*)((char*)Bs[s] + row*128 + ((l7^srow)<<4)) = pack8(pb0[i], pb1[i]);
    }
  };

  const int kt0 = blockIdx.y * kiters, kend = kt0 + kiters;
  stageA(0, kt0); prefB(kt0); commitB(0);
  __syncthreads();

  int cur = 0;
  for (int kt = kt0; kt < kend; ++kt){
    if (kt+1 < kend){ stageA(cur^1, kt+1); prefB(kt+1); }
    #pragma unroll
    for (int kk=0;kk<2;++kk){
      bf16x8 af[4], bq[4];
      const int sw = (kk*64 + (lane>>4)*16) ^ (l7<<4);
      #pragma unroll
      for (int i=0;i<4;++i) af[i] = *(const bf16x8*)((const char*)As[cur] + (wr*64+i*16+(lane&15))*128 + sw);
      #pragma unroll
      for (int j=0;j<4;++j) bq[j] = *(const bf16x8*)((const char*)Bs[cur] + (wc*64+j*16+(lane&15))*128 + sw);
      #pragma unroll
      for (int i=0;i<4;++i)
        #pragma unroll
        for (int j=0;j<4;++j)
          acc[i][j] = mfma16(af[i], bq[j], acc[i][j]);
    }
    if (kt+1 < kend) commitB(cur^1);
    __syncthreads();
    cur ^= 1;
  }
  const int lo = lane&15, hi = lane>>4;
  #pragma unroll
  for (int i=0;i<4;++i){
    #pragma unroll
    for (int j=0;j<4;++j){
      int n = nb*128 + wc*64 + j*16 + lo - noff;
      #pragma unroll
      for (int q=0;q<4;++q){
        int m = wr*64 + i*16 + hi*4 + q;
        float v = acc[i][j][q];
        if constexpr (MODE==2){
          if (n < Vv) O0[(size_t)m*Vv + n] = v + bias[n];
        } else {
          atomicAdd(&Ot[(size_t)m*ostride + n], v);
        }
      }
    }
  }
}

// ---------------- softmax over S=512 per batch row ----------------
__global__ void k_softmax(const float* __restrict__ scores, float* __restrict__ attn)
{
  __shared__ float red[512];
  const int b = blockIdx.x, tid = threadIdx.x;
  float v = scores[b*Ss + tid];
  red[tid] = v; __syncthreads();
  for (int off=256; off>0; off>>=1){ if (tid<off) red[tid] = fmaxf(red[tid], red[tid+off]); __syncthreads(); }
  float mx = red[0]; __syncthreads();
  float e = __expf(v - mx);
  red[tid] = e; __syncthreads();
  for (int off=256; off>0; off>>=1){ if (tid<off) red[tid] += red[tid+off]; __syncthreads(); }
  attn[b*Ss + tid] = e / red[0];
}

// ---------------- ctx partial: bf16 enc, 4 row-chunks of 128, vectorized ----------------
__global__ void k_ctx_bf16(const short* __restrict__ encb, const float* __restrict__ attn,
                           float* __restrict__ ctxp)
{
  __shared__ float a[128];
  const int bid = blockIdx.x, b = bid>>2, ch = bid&3, tid = threadIdx.x;
  if (tid < 128) a[tid] = attn[b*Ss + ch*128 + tid];
  __syncthreads();
  const short* e0 = encb + (size_t)(b*Ss + ch*128)*TWOH + tid*8;
  float s[8] = {};
  for (int r=0; r<128; ++r){
    bf16x8 v = *(const bf16x8*)(e0 + (size_t)r*TWOH);
    float w = a[r];
    #pragma unroll
    for (int j=0;j<8;++j) s[j] += w * bf2f(v[j]);
  }
  float* o = ctxp + (size_t)ch*Bb*TWOH + (size_t)b*TWOH + tid*8;
  #pragma unroll
  for (int j=0;j<8;++j) o[j] = s[j];
}

__global__ void k_ctxfin(const float* __restrict__ ctxp, short* __restrict__ xb)
{
  const int g = blockIdx.x*256 + threadIdx.x;
  const int b = g >> 11, col = g & 2047;
  const int N = Bb*TWOH;
  float v = ctxp[g] + ctxp[N+g] + ctxp[2*N+g] + ctxp[3*N+g];
  xb[b*2560 + 512 + col] = f2bf(v);
}

// fallback (small ws): fp32 enc, writes xb directly
__global__ void k_ctx_f32(const float* __restrict__ enc, const float* __restrict__ attn,
                          short* __restrict__ xb)
{
  __shared__ float a[512];
  const int ch = blockIdx.x, b = blockIdx.y, tid = threadIdx.x;
  a[tid]     = attn[b*Ss + tid];
  a[tid+256] = attn[b*Ss + tid + 256];
  __syncthreads();
  const float* e0 = enc + (size_t)b*Ss*TWOH + ch*256 + tid;
  float s0=0.f, s1=0.f, s2=0.f, s3=0.f;
  for (int s=0; s<512; s+=4){
    s0 += a[s]   * e0[(size_t)(s  )*TWOH];
    s1 += a[s+1] * e0[(size_t)(s+1)*TWOH];
    s2 += a[s+2] * e0[(size_t)(s+2)*TWOH];
    s3 += a[s+3] * e0[(size_t)(s+3)*TWOH];
  }
  xb[b*2560 + 512 + ch*256 + tid] = f2bf(s0+s1+s2+s3);
}

// ---------------- GRU gates + h_new ----------------
__global__ void k_gates(const float* __restrict__ gx, const float* __restrict__ gh,
                        const float* __restrict__ b_ih, const float* __restrict__ b_hh,
                        const float* __restrict__ h, float* __restrict__ hnew_out,
                        short* __restrict__ hnewb)
{
  const int gid = blockIdx.x*256 + threadIdx.x;
  const int b = gid >> 10, j = gid & 1023;
  float xr = gx[b*3072 + j]        + b_ih[j];
  float xz = gx[b*3072 + 1024 + j] + b_ih[1024+j];
  float xn = gx[b*3072 + 2048 + j] + b_ih[2048+j];
  float hr = gh[b*3072 + j]        + b_hh[j];
  float hz = gh[b*3072 + 1024 + j] + b_hh[1024+j];
  float hn = gh[b*3072 + 2048 + j] + b_hh[2048+j];
  float r = 1.f/(1.f + __expf(-(xr+hr)));
  float z = 1.f/(1.f + __expf(-(xz+hz)));
  float n = tanhf(xn + r*hn);
  float hv = (1.f - z)*n + z*h[b*Hh + j];
  hnew_out[gid] = hv;
  hnewb[gid] = f2bf(hv);
}

extern "C" void kernel_launch(void* const* d_in, const int* in_sizes, int n_in,
                              void* d_out, int out_size, void* d_ws, size_t ws_size,
                              hipStream_t stream)
{
  const int*   dec   = (const int*)  d_in[0];
  const float* h     = (const float*)d_in[1];
  const float* enc   = (const float*)d_in[2];
  const float* emb   = (const float*)d_in[3];
  const float* W_ah  = (const float*)d_in[4];
  const float* b_ah  = (const float*)d_in[5];
  const float* W_ae  = (const float*)d_in[6];
  const float* b_ae  = (const float*)d_in[7];
  const float* wsc   = (const float*)d_in[8];
  const float* W_ih  = (const float*)d_in[9];
  const float* W_hh  = (const float*)d_in[10];
  const float* b_ih  = (const float*)d_in[11];
  const float* b_hh  = (const float*)d_in[12];
  const float* W_out = (const float*)d_in[13];
  const float* b_out = (const float*)d_in[14];
  float* out = (float*)d_out;
  float* hnew_out = out + (size_t)Bb*Vv;

  char* w = (char*)d_ws;
  float* scores = (float*)w;  w += (size_t)65536*4;    // zeroed (atomic target)
  float* ahb    = (float*)w;  w += (size_t)131072*4;   // zeroed
  float* ghb    = (float*)w;  w += (size_t)393216*4;   // zeroed
  float* gxb    = (float*)w;  w += (size_t)393216*4;   // zeroed
  size_t zero_bytes = (size_t)(w - (char*)d_ws);
  float* attn   = (float*)w;  w += (size_t)65536*4;
  short* waeb   = (short*)w;  w += (size_t)2097152*2;
  short* xb     = (short*)w;  w += (size_t)128*2560*2;
  short* hb     = (short*)w;  w += (size_t)131072*2;
  short* hnb    = (short*)w;  w += (size_t)131072*2;
  float* ctxp   = (float*)w;  w += (size_t)4*Bb*TWOH*4;
  short* encb   = (short*)w;  w += (size_t)65536*2048*2;
  const bool big = ((size_t)(w - (char*)d_ws) <= ws_size);

  hipMemsetAsync(d_ws, 0, zero_bytes, stream);
  k_prep<<<4096, 256, 0, stream>>>(W_ae, waeb, h, hb, dec, emb, xb);
  k_gemm128<0><<<dim3(32,2), 256, 0, stream>>>(hb, 1024, W_ah, W_hh, ahb, ghb, nullptr, 8);
  k_scores_fuse<<<2048, 512, 0, stream>>>(enc, big ? encb : nullptr, waeb,
                                          ahb, b_ah, b_ae, wsc, scores);
  k_softmax<<<128, 512, 0, stream>>>(scores, attn);
  if (big){
    k_ctx_bf16<<<512, 256, 0, stream>>>(encb, attn, ctxp);
    k_ctxfin<<<1024, 256, 0, stream>>>(ctxp, xb);
  } else {
    k_ctx_f32<<<dim3(8,128), 256, 0, stream>>>(enc, attn, xb);
  }
  k_gemm128<1><<<dim3(24,4), 256, 0, stream>>>(xb, 2560, W_ih, nullptr, gxb, nullptr, nullptr, 10);
  k_gates<<<512, 256, 0, stream>>>(gxb, ghb, b_ih, b_hh, h, hnew_out, hnb);
  k_gemm128<2><<<dim3(393,1), 256, 0, stream>>>(hnb, 1024, W_out, nullptr, out, nullptr, b_out, 16);
}

// Round 16
// 528.152 us; speedup vs baseline: 1.0942x; 1.0942x over previous
//
#include <hip/hip_runtime.h>
#include <hip/hip_bf16.h>

#define DEVI __device__ __forceinline__

typedef short bf16x8 __attribute__((ext_vector_type(8)));
typedef float f32x4  __attribute__((ext_vector_type(4)));

static constexpr int Bb   = 128;
static constexpr int Ss   = 512;
static constexpr int Hh   = 1024;
static constexpr int Ee   = 512;
static constexpr int Vv   = 50257;
static constexpr int TWOH = 2048;

DEVI short f2bf(float f){ __hip_bfloat16 h = __float2bfloat16(f); return *reinterpret_cast<short*>(&h); }
DEVI float bf2f(short s){ __hip_bfloat16 h = *reinterpret_cast<__hip_bfloat16*>(&s); return __bfloat162float(h); }

DEVI float tanh_fast(float x){            // 1 - 2/(e^2x + 1): ±inf-safe, ~1e-7 rel err
  float e = __expf(2.0f*x);
  return 1.0f - 2.0f/(e + 1.0f);
}

DEVI bf16x8 pack8(f32x4 a, f32x4 b){
  bf16x8 v;
  v[0]=f2bf(a[0]); v[1]=f2bf(a[1]); v[2]=f2bf(a[2]); v[3]=f2bf(a[3]);
  v[4]=f2bf(b[0]); v[5]=f2bf(b[1]); v[6]=f2bf(b[2]); v[7]=f2bf(b[3]);
  return v;
}

DEVI void gld_lds16(const void* g, void* l){
  __builtin_amdgcn_global_load_lds((const __attribute__((address_space(1))) void*)g,
                                   (__attribute__((address_space(3))) void*)l, 16, 0, 0);
}

DEVI f32x4 mfma16(bf16x8 a, bf16x8 b, f32x4 c){
  return __builtin_amdgcn_mfma_f32_16x16x32_bf16(a, b, c, 0, 0, 0);
}

// ---------------- prep: convert W_ae->bf16, h->bf16, gather emb into x_bf16 ----------------
__global__ void k_prep(const float* __restrict__ wae, short* __restrict__ waeb,
                       const float* __restrict__ h, short* __restrict__ hb,
                       const int* __restrict__ dec_in, const float* __restrict__ emb,
                       short* __restrict__ xb)
{
  const int total_wae = Hh*TWOH;
  const int total_h   = Bb*Hh;
  const int total_emb = Bb*Ee;
  const int total = total_wae + total_h + total_emb;
  for (int i = blockIdx.x*blockDim.x + threadIdx.x; i < total; i += gridDim.x*blockDim.x){
    if (i < total_wae) waeb[i] = f2bf(wae[i]);
    else if (i < total_wae + total_h){ int j = i - total_wae; hb[j] = f2bf(h[j]); }
    else {
      int j = i - total_wae - total_h;
      int b = j >> 9, e = j & 511;
      xb[b*2560 + e] = f2bf(emb[(size_t)dec_in[b]*Ee + e]);
    }
  }
}

// ---------------- scores GEMM, FUSED fp32->bf16, ISSUE-EARLY / COMMIT-LATE ------
// (r14 configuration — best measured: 403us kernel, 535us total.)
// 256x256 tile, 8 waves (2M x 4N), BK=64, A+B double-buffered (128KB LDS).
// T14/G15: pin {STB(t+1); PREFA(t+1)} at tile top with sched_barrier(0);
// COMMITA+STOREE at END of half2 (after all 64 MFMAs) -> full-tile (~1000cyc)
// prefetch cover. Ordering invariant: STB issued BEFORE PREFA, so COMMITA's
// pa-register vmcnt-wait retires STB(t+1) before the barrier releases waves
// into tile t+1 (in-order vmem retirement).
// nb==0 blocks persist converted regs to encb (linear copy) for k_ctx.
// XCD grouping: q&7 = XCD; 4 same-rt blocks share the fp32 A panel (2MB) in L2
// (measured FETCH 328MB).
__launch_bounds__(512)
__global__ void k_scores_fuse(const float* __restrict__ enc, short* __restrict__ encb,
                              const short* __restrict__ waeb,
                              const float* __restrict__ ahb, const float* __restrict__ b_ah,
                              const float* __restrict__ b_ae, const float* __restrict__ wsc,
                              float* __restrict__ scores)
{
  __shared__ __align__(16) char LDSB[131072];   // A: 2x32KB @0, B: 2x32KB @65536
  const int q  = blockIdx.x;
  const int xcd = q & 7, sl = q >> 3;
  const int rt = xcd*32 + (sl>>2), nb = sl & 3; // rt 0..255, nb 0..3 (bijective)
  const int tid = threadIdx.x, wid = tid>>6, lane = tid&63;
  const int wr = wid>>2, wc = wid&3;            // 2M x 4N waves
  const int srow = lane>>3, l7 = lane&7;
  const int lo = lane&15, hi4 = lane>>4;
  const int swk = (l7 ^ srow)*8;                // pre-swizzled source k-chunk (elems)

  const float* Ag = enc  + (size_t)rt*256*TWOH + (size_t)(wid*8+srow)*TWOH + swk;
  const short* Bg = waeb + (size_t)nb*256*TWOH + (size_t)(wid*8+srow)*TWOH + swk;
  short*       Eg = encb + (size_t)rt*256*TWOH + (size_t)(wid*8+srow)*TWOH + swk;
  const bool we = (nb == 0) && (encb != nullptr);

  char* AWc = LDSB + wid*1024 + lane*16;        // + buf*32768 + rnd*8192 (ds_write)
  char* BW  = LDSB + 65536 + wid*1024;          // + buf*32768 + rnd*8192 (gld_lds, lane implicit)
  const char* AR = LDSB + (wr*128 + lo)*128;    // + buf*32768 + i*2048 + sw
  const char* BR = LDSB + 65536 + (wc*64 + lo)*128;
  const int sw0 = (hi4*16) ^ (l7<<4);           // kk=0 swizzled byte offset
  const int sw1 = (64 + hi4*16) ^ (l7<<4);      // kk=1

  f32x4 acc[8][4] = {};
  f32x4 pa[4][2];                               // pending fp32 A regs (one set)

  auto STB = [&](int buf, int kt){
    #pragma unroll
    for (int rnd=0; rnd<4; ++rnd)
      gld_lds16(Bg + (size_t)rnd*64*TWOH + kt*64, BW + buf*32768 + rnd*8192);
  };
  auto PREFA = [&](int kt){
    #pragma unroll
    for (int rnd=0; rnd<4; ++rnd){
      const float* p = Ag + (size_t)rnd*64*TWOH + kt*64;
      pa[rnd][0] = *(const f32x4*)p; pa[rnd][1] = *(const f32x4*)(p+4);
    }
  };
  auto COMMITA = [&](int buf){
    #pragma unroll
    for (int rnd=0; rnd<4; ++rnd)
      *(bf16x8*)(AWc + buf*32768 + rnd*8192) = pack8(pa[rnd][0], pa[rnd][1]);
  };
  auto STOREE = [&](int kt){
    #pragma unroll
    for (int rnd=0; rnd<4; ++rnd)
      *(bf16x8*)(Eg + (size_t)rnd*64*TWOH + kt*64) = pack8(pa[rnd][0], pa[rnd][1]);
  };

  // prologue: STB first (older), then PREFA(0)->commit (pa-wait retires STB(0)),
  // persist, prefetch A(1); drain ds_writes; barrier.
  STB(0,0);
  PREFA(0); COMMITA(0);
  if (we) STOREE(0);
  PREFA(1);
  asm volatile("s_waitcnt lgkmcnt(0)" ::: "memory");
  __builtin_amdgcn_s_barrier();
  __builtin_amdgcn_sched_barrier(0);

  for (int t = 0; t < 32; ++t){
    const int cur = t&1, nxt = cur^1;
    const int aO = cur*32768, bO = cur*32768;
    bf16x8 af[4], bq[4];

    // ---- issue-early (pinned): B(t+1) gld_lds THEN A(t+1) reg loads ----
    if (t<31){ STB(nxt, t+1); PREFA(t+1); }
    __builtin_amdgcn_sched_barrier(0);

    // ---- half 1 (kk0): 32 MFMA ----
    #pragma unroll
    for (int j=0;j<4;++j) bq[j] = *(const bf16x8*)(BR + bO + j*2048 + sw0);
    #pragma unroll
    for (int i=0;i<4;++i) af[i] = *(const bf16x8*)(AR + aO + i*2048 + sw0);
    __builtin_amdgcn_s_setprio(1);
    #pragma unroll
    for (int i=0;i<4;++i)
      #pragma unroll
      for (int j=0;j<4;++j)
        acc[i][j] = mfma16(af[i], bq[j], acc[i][j]);
    __builtin_amdgcn_s_setprio(0);
    #pragma unroll
    for (int i=0;i<4;++i) af[i] = *(const bf16x8*)(AR + aO + (4+i)*2048 + sw0);
    __builtin_amdgcn_s_setprio(1);
    #pragma unroll
    for (int i=0;i<4;++i)
      #pragma unroll
      for (int j=0;j<4;++j)
        acc[4+i][j] = mfma16(af[i], bq[j], acc[4+i][j]);
    __builtin_amdgcn_s_setprio(0);

    // ---- half 2 (kk1): 32 MFMA ----
    #pragma unroll
    for (int j=0;j<4;++j) bq[j] = *(const bf16x8*)(BR + bO + j*2048 + sw1);
    #pragma unroll
    for (int i=0;i<4;++i) af[i] = *(const bf16x8*)(AR + aO + i*2048 + sw1);
    __builtin_amdgcn_s_setprio(1);
    #pragma unroll
    for (int i=0;i<4;++i)
      #pragma unroll
      for (int j=0;j<4;++j)
        acc[i][j] = mfma16(af[i], bq[j], acc[i][j]);
    __builtin_amdgcn_s_setprio(0);
    #pragma unroll
    for (int i=0;i<4;++i) af[i] = *(const bf16x8*)(AR + aO + (4+i)*2048 + sw1);
    __builtin_amdgcn_s_setprio(1);
    #pragma unroll
    for (int i=0;i<4;++i)
      #pragma unroll
      for (int j=0;j<4;++j)
        acc[4+i][j] = mfma16(af[i], bq[j], acc[4+i][j]);
    __builtin_amdgcn_s_setprio(0);

    // ---- commit-late: pa-wait retires STB(t+1) (older); drain ds_writes; barrier ----
    __builtin_amdgcn_sched_barrier(0);
    if (t<31){
      COMMITA(nxt);
      if (we) STOREE(t+1);
    }
    asm volatile("s_waitcnt lgkmcnt(0)" ::: "memory");
    __builtin_amdgcn_s_barrier();
    __builtin_amdgcn_sched_barrier(0);
  }
  // epilogue: scores[m] += sum_n tanh(ah[b,n]+b_ah+b_ae+ae)*w_score[n]
  const int b = rt >> 1;                        // 256-row tile = half a batch row
  float w4[4], t4[4];
  #pragma unroll
  for (int j=0;j<4;++j){
    int n = nb*256 + wc*64 + j*16 + lo;
    w4[j] = wsc[n];
    t4[j] = ahb[b*Hh + n] + b_ah[n] + b_ae[n];
  }
  #pragma unroll
  for (int i=0;i<8;++i){
    #pragma unroll
    for (int q2=0;q2<4;++q2){
      int m = rt*256 + wr*128 + i*16 + hi4*4 + q2;
      float s = 0.f;
      #pragma unroll
      for (int j=0;j<4;++j) s += tanh_fast(t4[j] + acc[i][j][q2]) * w4[j];
      s += __shfl_xor(s,1); s += __shfl_xor(s,2); s += __shfl_xor(s,4); s += __shfl_xor(s,8);
      if (lo == 0) atomicAdd(&scores[m], s);
    }
  }
}

// ---------------- generic 128-row GEMM: A[128,K] bf16 ws, B[N,K] fp32 global --------------
template<int MODE>
__launch_bounds__(256)
__global__ void k_gemm128(const short* __restrict__ A, int lda,
                          const float* __restrict__ B0, const float* __restrict__ B1,
                          float* __restrict__ O0, float* __restrict__ O1,
                          const float* __restrict__ bias, int kiters)
{
  __shared__ __align__(16) short As[2][128*64];
  __shared__ __align__(16) short Bs[2][128*64];
  const int nb = blockIdx.x;
  const int tid = threadIdx.x, wid = tid>>6, lane = tid&63;
  const int wr = wid>>1, wc = wid&1;
  const int srow = lane>>3, l7 = lane&7;
  const int swk = (l7 ^ srow) * 8;

  const float* Bt; int noff; float* Ot; int ostride;
  if constexpr (MODE==0){
    if (nb < 8){ Bt = B0; noff = 0;    Ot = O0; ostride = Hh;   }
    else       { Bt = B1; noff = 1024; Ot = O1; ostride = 3*Hh; }
  } else if constexpr (MODE==1){ Bt = B0; noff = 0; Ot = O0; ostride = 3*Hh; }
  else { Bt = B0; noff = 0; Ot = O0; ostride = Vv; }

  f32x4 acc[4][4] = {};
  f32x4 pb0[4], pb1[4];

  auto stageA = [&](int s, int kt){
    #pragma unroll
    for (int i=0;i<4;++i){
      int c = wid*4+i, row = c*8+srow;
      gld_lds16(A + (size_t)row*lda + kt*64 + swk, (char*)As[s] + c*1024);
    }
  };
  auto prefB = [&](int kt){
    #pragma unroll
    for (int i=0;i<4;++i){
      int row = (wid*4+i)*8+srow;
      int n = nb*128 + row - noff;
      if constexpr (MODE==2) n = (n > Vv-1) ? (Vv-1) : n;
      const float* bp = Bt + (size_t)n*lda + kt*64 + l7*8;
      pb0[i] = *(const f32x4*)bp; pb1[i] = *(const f32x4*)(bp+4);
    }
  };
  auto commitB = [&](int s){
    #pragma unroll
    for (int i=0;i<4;++i){
      int row = (wid*4+i)*8+srow;
      *(bf16x8*)((char*)Bs[s] + row*128 + ((l7^srow)<<4)) = pack8(pb0[i], pb1[i]);
    }
  };

  const int kt0 = blockIdx.y * kiters, kend = kt0 + kiters;
  stageA(0, kt0); prefB(kt0); commitB(0);
  __syncthreads();

  int cur = 0;
  for (int kt = kt0; kt < kend; ++kt){
    if (kt+1 < kend){ stageA(cur^1, kt+1); prefB(kt+1); }
    #pragma unroll
    for (int kk=0;kk<2;++kk){
      bf16x8 af[4], bq[4];
      const int sw = (kk*64 + (lane>>4)*16) ^ (l7<<4);
      #pragma unroll
      for (int i=0;i<4;++i) af[i] = *(const bf16x8*)((const char*)As[cur] + (wr*64+i*16+(lane&15))*128 + sw);
      #pragma unroll
      for (int j=0;j<4;++j) bq[j] = *(const bf16x8*)((const char*)Bs[cur] + (wc*64+j*16+(lane&15))*128 + sw);
      #pragma unroll
      for (int i=0;i<4;++i)
        #pragma unroll
        for (int j=0;j<4;++j)
          acc[i][j] = mfma16(af[i], bq[j], acc[i][j]);
    }
    if (kt+1 < kend) commitB(cur^1);
    __syncthreads();
    cur ^= 1;
  }
  const int lo = lane&15, hi = lane>>4;
  #pragma unroll
  for (int i=0;i<4;++i){
    #pragma unroll
    for (int j=0;j<4;++j){
      int n = nb*128 + wc*64 + j*16 + lo - noff;
      #pragma unroll
      for (int q=0;q<4;++q){
        int m = wr*64 + i*16 + hi*4 + q;
        float v = acc[i][j][q];
        if constexpr (MODE==2){
          if (n < Vv) O0[(size_t)m*Vv + n] = v + bias[n];
        } else {
          atomicAdd(&Ot[(size_t)m*ostride + n], v);
        }
      }
    }
  }
}

// ---------------- softmax over S=512 per batch row ----------------
__global__ void k_softmax(const float* __restrict__ scores, float* __restrict__ attn)
{
  __shared__ float red[512];
  const int b = blockIdx.x, tid = threadIdx.x;
  float v = scores[b*Ss + tid];
  red[tid] = v; __syncthreads();
  for (int off=256; off>0; off>>=1){ if (tid<off) red[tid] = fmaxf(red[tid], red[tid+off]); __syncthreads(); }
  float mx = red[0]; __syncthreads();
  float e = __expf(v - mx);
  red[tid] = e; __syncthreads();
  for (int off=256; off>0; off>>=1){ if (tid<off) red[tid] += red[tid+off]; __syncthreads(); }
  attn[b*Ss + tid] = e / red[0];
}

// ---------------- ctx partial: bf16 enc, 4 row-chunks of 128, vectorized ----------------
__global__ void k_ctx_bf16(const short* __restrict__ encb, const float* __restrict__ attn,
                           float* __restrict__ ctxp)
{
  __shared__ float a[128];
  const int bid = blockIdx.x, b = bid>>2, ch = bid&3, tid = threadIdx.x;
  if (tid < 128) a[tid] = attn[b*Ss + ch*128 + tid];
  __syncthreads();
  const short* e0 = encb + (size_t)(b*Ss + ch*128)*TWOH + tid*8;
  float s[8] = {};
  for (int r=0; r<128; ++r){
    bf16x8 v = *(const bf16x8*)(e0 + (size_t)r*TWOH);
    float w = a[r];
    #pragma unroll
    for (int j=0;j<8;++j) s[j] += w * bf2f(v[j]);
  }
  float* o = ctxp + (size_t)ch*Bb*TWOH + (size_t)b*TWOH + tid*8;
  #pragma unroll
  for (int j=0;j<8;++j) o[j] = s[j];
}

__global__ void k_ctxfin(const float* __restrict__ ctxp, short* __restrict__ xb)
{
  const int g = blockIdx.x*256 + threadIdx.x;
  const int b = g >> 11, col = g & 2047;
  const int N = Bb*TWOH;
  float v = ctxp[g] + ctxp[N+g] + ctxp[2*N+g] + ctxp[3*N+g];
  xb[b*2560 + 512 + col] = f2bf(v);
}

// fallback (small ws): fp32 enc, writes xb directly
__global__ void k_ctx_f32(const float* __restrict__ enc, const float* __restrict__ attn,
                          short* __restrict__ xb)
{
  __shared__ float a[512];
  const int ch = blockIdx.x, b = blockIdx.y, tid = threadIdx.x;
  a[tid]     = attn[b*Ss + tid];
  a[tid+256] = attn[b*Ss + tid + 256];
  __syncthreads();
  const float* e0 = enc + (size_t)b*Ss*TWOH + ch*256 + tid;
  float s0=0.f, s1=0.f, s2=0.f, s3=0.f;
  for (int s=0; s<512; s+=4){
    s0 += a[s]   * e0[(size_t)(s  )*TWOH];
    s1 += a[s+1] * e0[(size_t)(s+1)*TWOH];
    s2 += a[s+2] * e0[(size_t)(s+2)*TWOH];
    s3 += a[s+3] * e0[(size_t)(s+3)*TWOH];
  }
  xb[b*2560 + 512 + ch*256 + tid] = f2bf(s0+s1+s2+s3);
}

// ---------------- GRU gates + h_new ----------------
__global__ void k_gates(const float* __restrict__ gx, const float* __restrict__ gh,
                        const float* __restrict__ b_ih, const float* __restrict__ b_hh,
                        const float* __restrict__ h, float* __restrict__ hnew_out,
                        short* __restrict__ hnewb)
{
  const int gid = blockIdx.x*256 + threadIdx.x;
  const int b = gid >> 10, j = gid & 1023;
  float xr = gx[b*3072 + j]        + b_ih[j];
  float xz = gx[b*3072 + 1024 + j] + b_ih[1024+j];
  float xn = gx[b*3072 + 2048 + j] + b_ih[2048+j];
  float hr = gh[b*3072 + j]        + b_hh[j];
  float hz = gh[b*3072 + 1024 + j] + b_hh[1024+j];
  float hn = gh[b*3072 + 2048 + j] + b_hh[2048+j];
  float r = 1.f/(1.f + __expf(-(xr+hr)));
  float z = 1.f/(1.f + __expf(-(xz+hz)));
  float n = tanhf(xn + r*hn);
  float hv = (1.f - z)*n + z*h[b*Hh + j];
  hnew_out[gid] = hv;
  hnewb[gid] = f2bf(hv);
}

extern "C" void kernel_launch(void* const* d_in, const int* in_sizes, int n_in,
                              void* d_out, int out_size, void* d_ws, size_t ws_size,
                              hipStream_t stream)
{
  const int*   dec   = (const int*)  d_in[0];
  const float* h     = (const float*)d_in[1];
  const float* enc   = (const float*)d_in[2];
  const float* emb   = (const float*)d_in[3];
  const float* W_ah  = (const float*)d_in[4];
  const float* b_ah  = (const float*)d_in[5];
  const float* W_ae  = (const float*)d_in[6];
  const float* b_ae  = (const float*)d_in[7];
  const float* wsc   = (const float*)d_in[8];
  const float* W_ih  = (const float*)d_in[9];
  const float* W_hh  = (const float*)d_in[10];
  const float* b_ih  = (const float*)d_in[11];
  const float* b_hh  = (const float*)d_in[12];
  const float* W_out = (const float*)d_in[13];
  const float* b_out = (const float*)d_in[14];
  float* out = (float*)d_out;
  float* hnew_out = out + (size_t)Bb*Vv;

  char* w = (char*)d_ws;
  float* scores = (float*)w;  w += (size_t)65536*4;    // zeroed (atomic target)
  float* ahb    = (float*)w;  w += (size_t)131072*4;   // zeroed
  float* ghb    = (float*)w;  w += (size_t)393216*4;   // zeroed
  float* gxb    = (float*)w;  w += (size_t)393216*4;   // zeroed
  size_t zero_bytes = (size_t)(w - (char*)d_ws);
  float* attn   = (float*)w;  w += (size_t)65536*4;
  short* waeb   = (short*)w;  w += (size_t)2097152*2;
  short* xb     = (short*)w;  w += (size_t)128*2560*2;
  short* hb     = (short*)w;  w += (size_t)131072*2;
  short* hnb    = (short*)w;  w += (size_t)131072*2;
  float* ctxp   = (float*)w;  w += (size_t)4*Bb*TWOH*4;
  short* encb   = (short*)w;  w += (size_t)65536*2048*2;
  const bool big = ((size_t)(w - (char*)d_ws) <= ws_size);

  hipMemsetAsync(d_ws, 0, zero_bytes, stream);
  k_prep<<<4096, 256, 0, stream>>>(W_ae, waeb, h, hb, dec, emb, xb);
  k_gemm128<0><<<dim3(32,2), 256, 0, stream>>>(hb, 1024, W_ah, W_hh, ahb, ghb, nullptr, 8);
  k_scores_fuse<<<1024, 512, 0, stream>>>(enc, big ? encb : nullptr, waeb,
                                          ahb, b_ah, b_ae, wsc, scores);
  k_softmax<<<128, 512, 0, stream>>>(scores, attn);
  if (big){
    k_ctx_bf16<<<512, 256, 0, stream>>>(encb, attn, ctxp);
    k_ctxfin<<<1024, 256, 0, stream>>>(ctxp, xb);
  } else {
    k_ctx_f32<<<dim3(8,128), 256, 0, stream>>>(enc, attn, xb);
  }
  k_gemm128<1><<<dim3(24,4), 256, 0, stream>>>(xb, 2560, W_ih, nullptr, gxb, nullptr, nullptr, 10);
  k_gates<<<512, 256, 0, stream>>>(gxb, ghb, b_ih, b_hh, h, hnew_out, hnb);
  k_gemm128<2><<<dim3(393,1), 256, 0, stream>>>(hnb, 1024, W_out, nullptr, out, nullptr, b_out, 16);
}